// Round 4
// baseline (157.251 us; speedup 1.0000x reference)
//
#include <hip/hip_runtime.h>

// GraphConv B=256,N=512,D=6,F=128,MAX_DEG=6.
// R9 post-mortem: fused kernel 68us but NO pipe >20% (VALU 12, HBM 19, MFMA
// 2.5, occ 20). Cycle audit: ~80K/163K cycles unaccounted = latency+barriers
// at 2 waves/SIMD; phase-A branchless gather keeps 12 nbr reads always-active
// (avg degree 2.5); phase-B has 24 staging barriers. R10: (1) 1024 threads
// (16 waves, 4/SIMD), thread-pair per row in phase A; (2) degree-sorted
// branchy gather via rlist order -> whole-wave execz skip, ~2.2x less LDS;
// (3) phase-B B-frags direct from global Wt (L2-hot, same as R6 k2 A-path):
// no W staging, zero phase-B barriers, flattened item loop.

typedef short bf16x8 __attribute__((ext_vector_type(8)));
typedef float f32x4  __attribute__((ext_vector_type(4)));
typedef unsigned short ushort_t;
typedef unsigned int uint_t;

constexpr int Nn = 512;
constexpr int Ff = 128;

// ws: Wt bf16 [6][128][128] ([d][n][k])
constexpr size_t WS_NEEDED = 196608;

__device__ inline ushort_t f2bf(float f) {              // round-to-nearest-even
    uint_t u = __float_as_uint(f);
    return (ushort_t)((u + 0x7FFFu + ((u >> 16) & 1u)) >> 16);
}

__device__ inline bool detect_is64(const int* edges32) {
    // int64 edges: odd dwords are sign-extension words in {0,-1}.
    int probe = edges32[2 * (threadIdx.x & 63) + 1];
    return __any(probe > 0) == 0;
}

// ---------------- k0: W fp32 [d][k][n] -> Wt bf16 [d][n][k] ----------------
__global__ __launch_bounds__(1024)
void k0_wt(const float* __restrict__ W, ushort_t* __restrict__ Wt) {
    int L = blockIdx.x * 1024 + threadIdx.x;     // 96 blocks x 1024 = 98304
    int d = L >> 14, rem = L & 16383;
    int n = rem >> 7, k = rem & 127;
    Wt[L] = f2bf(W[(d << 14) + (k << 7) + n]);   // W is 384KB -> L2-resident
}

// ---------------- fused: one molecule per block, 1024 threads ----------------
// 16 waves = 4/SIMD. Phase A: thread pair (2i,2i+1) owns gather row rlist[i],
// each handles 4 floats/slice. Phase B: barrier-free flattened MFMA items.
__global__ __launch_bounds__(1024, 4)
void k_fused(const float* __restrict__ atoms,
             const int*   __restrict__ edges32,
             const ushort_t* __restrict__ Wt,
             const float* __restrict__ bias,
             float* __restrict__ out) {
    const int tid = threadIdx.x;
    const int mol = blockIdx.x;
    const bool is64 = detect_is64(edges32);      // convergent

    __shared__ ushort_t summed[Nn * 136];        // 139264 B (pad 136: 16B-aligned rows)
    __shared__ float4   abuf4[Nn * 2];           // 16384 B: one 8-float slice, swizzled
    __shared__ ushort_t rlist[Nn];               // 1024 B: row ids grouped by degree
    __shared__ int hist[6], base_sh[8];

    // --- prefetch atom slice 0 (floats 0..7 of all rows): 1 float4/thread ---
    const float4* gsrc = (const float4*)(atoms + (size_t)mol * (Nn * Ff));
    const int arow = tid >> 1, ac = tid & 1;     // natural staging coords
    float4 pf = gsrc[arow * 32 + ac];

    // --- phase 0: degree ranks (threads < 512; 1 row each) ---
    if (tid < 6) hist[tid] = 0;
    __syncthreads();
    int deg = 0, rk = 0;
    if (tid < Nn) {
        const size_t eb = (size_t)mol * (Nn * 6) + (size_t)tid * 6;
        #pragma unroll
        for (int j = 0; j < 6; j++) {
            int e = is64 ? edges32[(eb + j) * 2] : edges32[eb + j];
            deg += (e >= 0) ? 1 : 0;
        }
        if (deg > 5) deg = 5;                    // input spec: deg<=5; guard OOB
        rk = atomicAdd(&hist[deg], 1);
    }
    __syncthreads();
    if (tid == 0) {
        int a = 0;
        #pragma unroll
        for (int d = 0; d < 6; d++) { base_sh[d] = a; a += hist[d]; }
    }
    __syncthreads();
    if (tid < Nn) rlist[base_sh[deg] + rk] = (ushort_t)tid;
    // land slice-0 prefetch. Swizzle: granule g of row r at [2r + (g ^ (r&1))]
    abuf4[2 * arow + (ac ^ (arow & 1))] = pf;
    __syncthreads();                             // rlist + abuf ready

    // --- my gather row (rlist order -> degree-uniform waves) + its edges ---
    const int pr = tid >> 1, h = tid & 1;
    const int R = rlist[pr];
    int er[6];
    {
        const size_t eb = (size_t)mol * (Nn * 6) + (size_t)R * 6;
        #pragma unroll
        for (int j = 0; j < 6; j++)
            er[j] = is64 ? edges32[(eb + j) * 2] : edges32[eb + j];
    }

    // --- phase A: 16 slices of 8 floats; pair handles 4 floats each ---
    for (int s = 0; s < 16; s++) {
        if (s < 15) pf = gsrc[arow * 32 + (s + 1) * 2 + ac];   // issue early
        float4 a = abuf4[2 * R + (h ^ (R & 1))];               // self
        #pragma unroll
        for (int j = 0; j < 6; j++) {            // degree-uniform -> execz skip
            int e = er[j];
            if (e >= 0) {
                float4 v = abuf4[2 * e + (h ^ (e & 1))];
                a.x += v.x; a.y += v.y; a.z += v.z; a.w += v.w;
            }
        }
        uint2 o;
        o.x = (uint_t)f2bf(a.x) | ((uint_t)f2bf(a.y) << 16);
        o.y = (uint_t)f2bf(a.z) | ((uint_t)f2bf(a.w) << 16);
        *(uint2*)&summed[R * 136 + s * 8 + h * 4] = o;
        __syncthreads();                         // all abuf reads done
        if (s < 15) {
            abuf4[2 * arow + (ac ^ (arow & 1))] = pf;
            __syncthreads();                     // abuf ready for next gather
        }
    }
    // (s=15 ended with barrier: summed complete)

    // --- phase B: flattened barrier-free MFMA items, B-frags from global ---
    const int lane = tid & 63, wid = tid >> 6;   // wid 0..15
    const int kq = lane >> 4, ml = lane & 15;

    int cnts[6], cbase[6], Tp[7];
    {
        int a = 0, b = 0;
        #pragma unroll
        for (int d = 0; d < 6; d++) {
            cnts[d] = hist[d];
            cbase[d] = b; b += cnts[d];
            Tp[d] = a; a += ((cnts[d] + 15) >> 4) * 4;   // items = Td * 4 col-pairs
        }
        Tp[6] = a;
    }
    const int items = Tp[6];

    for (int it = wid; it < items; it += 16) {
        int d = 0;
        #pragma unroll
        for (int dd = 1; dd < 6; dd++) if (it >= Tp[dd]) d = dd;
        const int loc = it - Tp[d];
        const int ti = loc >> 2, ci = loc & 3;   // row-tile, col-pair
        const int cn = cnts[d], cb = cbase[d];

        int lidx = ti * 16 + ml;
        int cl = (lidx < cn) ? lidx : cn - 1;    // clamp; stores masked
        int row = rlist[cb + cl];
        bf16x8 af[4];                            // A: m=ml, k=kq*8+k0*32
        #pragma unroll
        for (int k0 = 0; k0 < 4; k0++)
            af[k0] = *(const bf16x8*)&summed[row * 136 + kq * 8 + k0 * 32];
        int orw[4];                              // C/D rows: kq*4+reg
        #pragma unroll
        for (int r = 0; r < 4; r++) {
            int li = ti * 16 + kq * 4 + r;
            orw[r] = (li < cn) ? (int)rlist[cb + li] : -1;
        }
        const ushort_t* wg = Wt + (size_t)d * 16384;
        #pragma unroll
        for (int n2 = 0; n2 < 2; n2++) {
            const int nt = ci * 2 + n2;
            bf16x8 bfr[4];                       // B: n=ml, k=kq*8+k0*32 (global, L2-hot)
            #pragma unroll
            for (int k0 = 0; k0 < 4; k0++)
                bfr[k0] = *(const bf16x8*)&wg[(nt * 16 + ml) * 128 + k0 * 32 + kq * 8];
            f32x4 c = {0.f, 0.f, 0.f, 0.f};
            #pragma unroll
            for (int k0 = 0; k0 < 4; k0++)
                c = __builtin_amdgcn_mfma_f32_16x16x32_bf16(af[k0], bfr[k0], c, 0, 0, 0);
            const int col = nt * 16 + ml;
            const float bc = bias[d * Ff + col];
            #pragma unroll
            for (int r = 0; r < 4; r++) {
                if (orw[r] >= 0) {
                    float v = c[r] + bc;
                    out[((size_t)mol * Nn + orw[r]) * Ff + col] = v > 0.f ? v : 0.f;
                }
            }
        }
    }
}

// ---------------- fallback (round-1 kernel) if ws too small ----------------
__global__ __launch_bounds__(128, 2)
void graphconv_fallback(const float* __restrict__ atoms,
                        const int* __restrict__ edges_raw,
                        const float* __restrict__ W,
                        const float* __restrict__ bias,
                        float* __restrict__ out) {
    const int tid = threadIdx.x;
    const int d = blockIdx.x % 6;
    const int k = blockIdx.x / 6;
    const int a0 = k * 256;
    __shared__ int eds[256 * 6];
    __shared__ int list[256];
    __shared__ int cnt;
    __shared__ float sv[2][Ff];
    bool is64;
    { int v = edges_raw[2 * (tid & 63) + 1]; is64 = (__ballot(v > 0) == 0ull); }
    if (!is64) { for (int i = tid; i < 256 * 6; i += 128) eds[i] = edges_raw[a0 * 6 + i]; }
    else       { for (int i = tid; i < 256 * 6; i += 128) eds[i] = edges_raw[2 * (a0 * 6 + i)]; }
    if (tid == 0) cnt = 0;
    __syncthreads();
    for (int i = tid; i < 256; i += 128) {
        int deg = 0;
        #pragma unroll
        for (int j = 0; j < 6; j++) deg += (eds[i * 6 + j] != -1) ? 1 : 0;
        if (deg == d) { int p = atomicAdd(&cnt, 1); list[p] = i; }
    }
    float Wreg[Ff];
    { const float* Wd = W + (size_t)d * Ff * Ff;
      #pragma unroll
      for (int f = 0; f < Ff; f++) Wreg[f] = Wd[f * Ff + tid]; }
    const float breg = bias[d * Ff + tid];
    __syncthreads();
    const int n = cnt;
    const float* batch_atoms = atoms + (size_t)(a0 / Nn) * Nn * Ff;
    const int row0 = a0 % Nn;
    for (int ii = 0; ii < n; ii++) {
        const int i = list[ii];
        float s = batch_atoms[(row0 + i) * Ff + tid];
        #pragma unroll
        for (int j = 0; j < 6; j++) {
            int e = eds[i * 6 + j];
            if (e != -1) s += batch_atoms[e * Ff + tid];
        }
        float* buf = sv[ii & 1];
        buf[tid] = s;
        __syncthreads();
        float acc = breg;
        const float4* sv4 = (const float4*)buf;
        #pragma unroll
        for (int fc = 0; fc < Ff / 4; fc++) {
            float4 x = sv4[fc];
            acc = fmaf(x.x, Wreg[4 * fc + 0], acc);
            acc = fmaf(x.y, Wreg[4 * fc + 1], acc);
            acc = fmaf(x.z, Wreg[4 * fc + 2], acc);
            acc = fmaf(x.w, Wreg[4 * fc + 3], acc);
        }
        out[(size_t)(a0 + i) * Ff + tid] = fmaxf(acc, 0.0f);
    }
}

extern "C" void kernel_launch(void* const* d_in, const int* in_sizes, int n_in,
                              void* d_out, int out_size, void* d_ws, size_t ws_size,
                              hipStream_t stream) {
    const float* atoms = (const float*)d_in[0];
    const int*   edges = (const int*)d_in[1];
    const float* W     = (const float*)d_in[2];
    const float* bias  = (const float*)d_in[3];
    float*       outp  = (float*)d_out;

    if (ws_size >= WS_NEEDED) {
        ushort_t* Wt = (ushort_t*)d_ws;
        k0_wt<<<96, 1024, 0, stream>>>(W, Wt);
        k_fused<<<256, 1024, 0, stream>>>(atoms, edges, Wt, bias, outp);
    } else {
        graphconv_fallback<<<3072, 128, 0, stream>>>(atoms, edges, W, bias, outp);
    }
}